// Round 1
// baseline (12.908 us; speedup 1.0000x reference)
//
#include <hip/hip_runtime.h>
#include <hip/hip_bf16.h>

#define NFEAT  64
#define KDIM   128
#define NPOS   1024
#define NBATCH 4
#define BT     128   // output tile (both dims)
#define LDT    136   // padded LDS leading dim in halves (16B-aligned rows, 2-way banks)

typedef _Float16 half8  __attribute__((ext_vector_type(8)));
typedef float    floatx4 __attribute__((ext_vector_type(4)));

// out[b,i,j] = sum_f a_f * cos(10*(x[b,j]-x[b,i])*w_f + b_f)
//            = sum_k A[b,i,k] * B[b,j,k],  K = 2*NFEAT = 128
// A[i, f]      = cos(10*w_f*x_i)          A[i, f+64] = sin(10*w_f*x_i)
// B[j, f]      = a_f*cos(10*w_f*x_j+b_f)  B[j, f+64] = a_f*sin(10*w_f*x_j+b_f)
__global__ __launch_bounds__(256, 2)
void fourier_bias_kernel(const float* __restrict__ frac,
                         const float* __restrict__ Wv,
                         const float* __restrict__ bv,
                         const float* __restrict__ av,
                         float* __restrict__ out) {
    __shared__ _Float16 sA[BT][LDT];
    __shared__ _Float16 sB[BT][LDT];

    const int tid = threadIdx.x;
    const int bz  = blockIdx.z;           // batch
    const int ti  = blockIdx.y * BT;      // output row tile origin (i)
    const int tj  = blockIdx.x * BT;      // output col tile origin (j)

    // ---- phase 1: fill feature tiles in LDS ----
    // thread tid handles feature f = tid&63, rows r0, r0+4, ..., r0+124
    const int   f  = tid & 63;
    const int   r0 = tid >> 6;            // 0..3
    const float wf = Wv[f] * 10.0f;       // fold SCALE into W
    const float bf = bv[f];
    const float af = av[f];
    const float* fb = frac + bz * NPOS;

    #pragma unroll 4
    for (int t = 0; t < 32; ++t) {
        const int row = r0 + t * 4;
        const float xi = fb[ti + row];    // wave-uniform (scalar load)
        float si, ci;
        __sincosf(wf * xi, &si, &ci);
        sA[row][f]      = (_Float16)ci;
        sA[row][f + 64] = (_Float16)si;
        const float xj = fb[tj + row];
        float sj, cj;
        __sincosf(wf * xj + bf, &sj, &cj);
        sB[row][f]      = (_Float16)(af * cj);
        sB[row][f + 64] = (_Float16)(af * sj);
    }
    __syncthreads();

    // ---- phase 2: 128x128 GEMM, K=128, f16 MFMA, fp32 accum ----
    const int lane = tid & 63;
    const int wid  = tid >> 6;            // 4 waves, 2x2
    const int wr   = (wid >> 1) * 64;     // wave row offset in tile
    const int wc   = (wid & 1) * 64;      // wave col offset in tile

    const int lrow = lane & 15;           // A/B fragment row/col within 16
    const int lkb  = lane >> 4;           // k sub-block (8 halves each)

    floatx4 acc[4][4];
    #pragma unroll
    for (int m = 0; m < 4; ++m)
        #pragma unroll
        for (int n = 0; n < 4; ++n)
            acc[m][n] = (floatx4){0.f, 0.f, 0.f, 0.f};

    #pragma unroll
    for (int t = 0; t < 4; ++t) {         // 4 K-steps of 32
        const int k = t * 32 + lkb * 8;
        half8 afr[4], bfr[4];
        #pragma unroll
        for (int m = 0; m < 4; ++m)
            afr[m] = *reinterpret_cast<const half8*>(&sA[wr + m * 16 + lrow][k]);
        #pragma unroll
        for (int n = 0; n < 4; ++n)
            bfr[n] = *reinterpret_cast<const half8*>(&sB[wc + n * 16 + lrow][k]);
        #pragma unroll
        for (int m = 0; m < 4; ++m)
            #pragma unroll
            for (int n = 0; n < 4; ++n)
                acc[m][n] = __builtin_amdgcn_mfma_f32_16x16x32_f16(
                    afr[m], bfr[n], acc[m][n], 0, 0, 0);
    }

    // ---- epilogue: C/D layout col = lane&15, row = (lane>>4)*4 + reg ----
    const int col  = lane & 15;
    const int row4 = (lane >> 4) * 4;
    #pragma unroll
    for (int m = 0; m < 4; ++m) {
        #pragma unroll
        for (int n = 0; n < 4; ++n) {
            const size_t gi = (size_t)(ti + wr + m * 16 + row4);
            const size_t gj = (size_t)(tj + wc + n * 16 + col);
            float* o = out + ((size_t)bz * NPOS + gi) * NPOS + gj;
            #pragma unroll
            for (int r = 0; r < 4; ++r)
                o[(size_t)r * NPOS] = acc[m][n][r];
        }
    }
}

extern "C" void kernel_launch(void* const* d_in, const int* in_sizes, int n_in,
                              void* d_out, int out_size, void* d_ws, size_t ws_size,
                              hipStream_t stream) {
    const float* frac = (const float*)d_in[0];  // [4,1024]
    const float* Wv   = (const float*)d_in[1];  // [1,64]
    const float* bv   = (const float*)d_in[2];  // [64]
    const float* av   = (const float*)d_in[3];  // [64]
    float* out = (float*)d_out;                 // [4,1024,1024]

    dim3 grid(NPOS / BT, NPOS / BT, NBATCH);
    fourier_bias_kernel<<<grid, dim3(256), 0, stream>>>(frac, Wv, bv, av, out);
}

// Round 2
// 12.604 us; speedup vs baseline: 1.0241x; 1.0241x over previous
//
#include <hip/hip_runtime.h>
#include <hip/hip_bf16.h>

#define NFEAT  64
#define KDIM   128
#define NPOS   1024
#define NBATCH 4
#define BT     128   // output tile (both dims)
#define LDT    136   // padded LDS leading dim in halves

typedef _Float16 half8  __attribute__((ext_vector_type(8)));
typedef float    floatx4 __attribute__((ext_vector_type(4)));

#define INV2PI 0.15915494309189535f

// out[b,i,j] = sum_f a_f * cos(10*(x[b,j]-x[b,i])*w_f + b_f)
//            = sum_k A[b,i,k] * B[b,j,k],  K = 2*NFEAT = 128
// A[i, f]      = cos(10*w_f*x_i)          A[i, f+64] = sin(10*w_f*x_i)
// B[j, f]      = a_f*cos(10*w_f*x_j+b_f)  B[j, f+64] = a_f*sin(10*w_f*x_j+b_f)
// Trig in revolution domain: v_sin_f32/v_cos_f32 compute sin/cos(S0*2pi),
// args here are <= ~1.7 revolutions -> no range reduction needed.
__global__ __launch_bounds__(256, 2)
void fourier_bias_kernel(const float* __restrict__ frac,
                         const float* __restrict__ Wv,
                         const float* __restrict__ bv,
                         const float* __restrict__ av,
                         float* __restrict__ out) {
    __shared__ _Float16 sA[BT][LDT];
    __shared__ _Float16 sB[BT][LDT];

    const int tid = threadIdx.x;
    const int bz  = blockIdx.z;           // batch
    const int ti  = blockIdx.y * BT;      // output row tile origin (i)
    const int tj  = blockIdx.x * BT;      // output col tile origin (j)

    // ---- phase 1: fill feature tiles in LDS (native trig, rev domain) ----
    const int   f      = tid & 63;
    const int   r0     = tid >> 6;        // 0..3
    const float wf_rev = Wv[f] * (10.0f * INV2PI);
    const float bf_rev = bv[f] * INV2PI;
    const float af     = av[f];
    const float* fb = frac + bz * NPOS;

    #pragma unroll 4
    for (int t = 0; t < 32; ++t) {
        const int row = r0 + t * 4;
        const float xi = fb[ti + row];    // wave-uniform
        const float ai = xi * wf_rev;
        sA[row][f]      = (_Float16)__builtin_amdgcn_cosf(ai);
        sA[row][f + 64] = (_Float16)__builtin_amdgcn_sinf(ai);
        const float xj = fb[tj + row];
        const float aj = __builtin_fmaf(xj, wf_rev, bf_rev);
        sB[row][f]      = (_Float16)(af * __builtin_amdgcn_cosf(aj));
        sB[row][f + 64] = (_Float16)(af * __builtin_amdgcn_sinf(aj));
    }
    __syncthreads();

    // ---- phase 2: 128x128 GEMM, K=128, f16 MFMA, fp32 accum ----
    const int lane = tid & 63;
    const int wid  = tid >> 6;            // 4 waves, 2x2
    const int wr   = (wid >> 1) * 64;     // wave row offset in tile
    const int wc   = (wid & 1) * 64;      // wave col offset in tile

    const int lrow = lane & 15;           // fragment row within 16
    const int lkb  = lane >> 4;           // k sub-block (8 halves each)

    floatx4 acc[4][4];
    #pragma unroll
    for (int m = 0; m < 4; ++m)
        #pragma unroll
        for (int n = 0; n < 4; ++n)
            acc[m][n] = (floatx4){0.f, 0.f, 0.f, 0.f};

    #pragma unroll
    for (int t = 0; t < 4; ++t) {         // 4 K-steps of 32
        const int k = t * 32 + lkb * 8;
        half8 afr[4], bfr[4];
        #pragma unroll
        for (int m = 0; m < 4; ++m)
            afr[m] = *reinterpret_cast<const half8*>(&sA[wr + m * 16 + lrow][k]);
        #pragma unroll
        for (int n = 0; n < 4; ++n)
            bfr[n] = *reinterpret_cast<const half8*>(&sB[wc + n * 16 + lrow][k]);
        #pragma unroll
        for (int m = 0; m < 4; ++m)
            #pragma unroll
            for (int n = 0; n < 4; ++n)
                acc[m][n] = __builtin_amdgcn_mfma_f32_16x16x32_f16(
                    afr[m], bfr[n], acc[m][n], 0, 0, 0);
    }

    // ---- epilogue: C/D layout col = lane&15, row = (lane>>4)*4 + reg ----
    const int col  = lane & 15;
    const int row4 = (lane >> 4) * 4;
    #pragma unroll
    for (int m = 0; m < 4; ++m) {
        #pragma unroll
        for (int n = 0; n < 4; ++n) {
            const size_t gi = (size_t)(ti + wr + m * 16 + row4);
            const size_t gj = (size_t)(tj + wc + n * 16 + col);
            float* o = out + ((size_t)bz * NPOS + gi) * NPOS + gj;
            #pragma unroll
            for (int r = 0; r < 4; ++r)
                o[(size_t)r * NPOS] = acc[m][n][r];
        }
    }
}

extern "C" void kernel_launch(void* const* d_in, const int* in_sizes, int n_in,
                              void* d_out, int out_size, void* d_ws, size_t ws_size,
                              hipStream_t stream) {
    const float* frac = (const float*)d_in[0];  // [4,1024]
    const float* Wv   = (const float*)d_in[1];  // [1,64]
    const float* bv   = (const float*)d_in[2];  // [64]
    const float* av   = (const float*)d_in[3];  // [64]
    float* out = (float*)d_out;                 // [4,1024,1024]

    dim3 grid(NPOS / BT, NPOS / BT, NBATCH);
    fourier_bias_kernel<<<grid, dim3(256), 0, stream>>>(frac, Wv, bv, av, out);
}

// Round 3
// 11.748 us; speedup vs baseline: 1.0987x; 1.0728x over previous
//
#include <hip/hip_runtime.h>
#include <hip/hip_bf16.h>

#define NPOS   1024
#define NBATCH 4
#define BT     64    // output tile (both dims)
#define LDT    136   // padded LDS leading dim in halves (K=128 + 8)

typedef _Float16 half8  __attribute__((ext_vector_type(8)));
typedef _Float16 half2x __attribute__((ext_vector_type(2)));
typedef float    floatx4 __attribute__((ext_vector_type(4)));

#define INV2PI 0.15915494309189535f

// out[b,i,j] = sum_f a_f * cos(10*(x[b,j]-x[b,i])*w_f + b_f)
//            = sum_k A[b,i,k] * B[b,j,k],  K = 2*NFEAT = 128
// K interleaved as (cos,sin) pairs: A[i,2f]=cos(t_i), A[i,2f+1]=sin(t_i),
// B[j,2f]=a_f cos(t_j+b_f), B[j,2f+1]=a_f sin(t_j+b_f); dot product is
// invariant under the K-permutation. Trig in revolution domain (v_sin/v_cos
// take revolutions; args <= ~1.7 rev, no range reduction needed).
//
// 64x64 tiles -> 1024 WGs = 4 WG/CU (16 waves/CU): independent WGs overlap
// trig/MFMA/store phases across each other (the R2 kernel at 1 WG/CU had
// nothing to overlap its 2.5us store drain with).
__global__ __launch_bounds__(256, 4)
void fourier_bias_kernel(const float* __restrict__ frac,
                         const float* __restrict__ Wv,
                         const float* __restrict__ bv,
                         const float* __restrict__ av,
                         float* __restrict__ out) {
    __shared__ _Float16 sA[BT][LDT];
    __shared__ _Float16 sB[BT][LDT];

    const int tid = threadIdx.x;
    const int bz  = blockIdx.z;           // batch
    const int ti  = blockIdx.y * BT;      // output row tile origin (i)
    const int tj  = blockIdx.x * BT;      // output col tile origin (j)

    // ---- phase 1: fill feature tiles in LDS ----
    const int   f      = tid & 63;
    const int   rt     = tid >> 6;        // 0..3
    const float wf_rev = Wv[f] * (10.0f * INV2PI);
    const float bf_rev = bv[f] * INV2PI;
    const float af     = av[f];
    const float* fb = frac + bz * NPOS;

    #pragma unroll
    for (int t = 0; t < 16; ++t) {
        const int row = rt + t * 4;       // rows rt, rt+4, ..., rt+60
        const float xi = fb[ti + row];    // wave-uniform
        const float ai = xi * wf_rev;
        half2x pa;
        pa[0] = (_Float16)__builtin_amdgcn_cosf(ai);
        pa[1] = (_Float16)__builtin_amdgcn_sinf(ai);
        *reinterpret_cast<half2x*>(&sA[row][2 * f]) = pa;   // 4B-aligned
        const float xj = fb[tj + row];
        const float aj = __builtin_fmaf(xj, wf_rev, bf_rev);
        half2x pb;
        pb[0] = (_Float16)(af * __builtin_amdgcn_cosf(aj));
        pb[1] = (_Float16)(af * __builtin_amdgcn_sinf(aj));
        *reinterpret_cast<half2x*>(&sB[row][2 * f]) = pb;
    }
    __syncthreads();

    // ---- phase 2: 64x64 GEMM, K=128, f16 MFMA, fp32 accum ----
    // 4 waves in 2x2; each wave owns a 32x32 sub-tile.
    const int lane = tid & 63;
    const int wid  = tid >> 6;
    const int wr   = (wid >> 1) * 32;
    const int wc   = (wid & 1) * 32;

    const int lrow = lane & 15;           // fragment row within 16
    const int lkb  = lane >> 4;           // k sub-block (8 halves each)

    floatx4 acc[2][2];
    #pragma unroll
    for (int m = 0; m < 2; ++m)
        #pragma unroll
        for (int n = 0; n < 2; ++n)
            acc[m][n] = (floatx4){0.f, 0.f, 0.f, 0.f};

    #pragma unroll
    for (int t = 0; t < 4; ++t) {         // 4 K-steps of 32
        const int k = t * 32 + lkb * 8;
        half8 afr[2], bfr[2];
        #pragma unroll
        for (int m = 0; m < 2; ++m)
            afr[m] = *reinterpret_cast<const half8*>(&sA[wr + m * 16 + lrow][k]);
        #pragma unroll
        for (int n = 0; n < 2; ++n)
            bfr[n] = *reinterpret_cast<const half8*>(&sB[wc + n * 16 + lrow][k]);
        #pragma unroll
        for (int m = 0; m < 2; ++m)
            #pragma unroll
            for (int n = 0; n < 2; ++n)
                acc[m][n] = __builtin_amdgcn_mfma_f32_16x16x32_f16(
                    afr[m], bfr[n], acc[m][n], 0, 0, 0);
    }

    // ---- epilogue: C/D layout col = lane&15, row = (lane>>4)*4 + reg ----
    const int col  = lane & 15;
    const int row4 = (lane >> 4) * 4;
    #pragma unroll
    for (int m = 0; m < 2; ++m) {
        #pragma unroll
        for (int n = 0; n < 2; ++n) {
            const size_t gi = (size_t)(ti + wr + m * 16 + row4);
            const size_t gj = (size_t)(tj + wc + n * 16 + col);
            float* o = out + ((size_t)bz * NPOS + gi) * NPOS + gj;
            #pragma unroll
            for (int r = 0; r < 4; ++r)
                o[(size_t)r * NPOS] = acc[m][n][r];
        }
    }
}

extern "C" void kernel_launch(void* const* d_in, const int* in_sizes, int n_in,
                              void* d_out, int out_size, void* d_ws, size_t ws_size,
                              hipStream_t stream) {
    const float* frac = (const float*)d_in[0];  // [4,1024]
    const float* Wv   = (const float*)d_in[1];  // [1,64]
    const float* bv   = (const float*)d_in[2];  // [64]
    const float* av   = (const float*)d_in[3];  // [64]
    float* out = (float*)d_out;                 // [4,1024,1024]

    dim3 grid(NPOS / BT, NPOS / BT, NBATCH);
    fourier_bias_kernel<<<grid, dim3(256), 0, stream>>>(frac, Wv, bv, av, out);
}